// Round 9
// baseline (238.998 us; speedup 1.0000x reference)
//
#include <hip/hip_runtime.h>
#include <hip/hip_cooperative_groups.h>
#include <math.h>

namespace cg = cooperative_groups;

#define N_NODES 100000
#define BSHIFT 9                 // 512-node buckets
#define NBUCK 256                // >= ceil(N/512)=196, pow2

typedef unsigned short bfu;
typedef unsigned int uint;
typedef __attribute__((ext_vector_type(8))) short short8v;   // 8 bf16 = 4 VGPRs
typedef __attribute__((ext_vector_type(4))) float f32x4;

__device__ __forceinline__ float bf2f(bfu u) {
    union { uint i; float f; } v; v.i = (uint)u << 16; return v.f;
}
__device__ __forceinline__ bfu f2bf(float f) {   // round-to-nearest-even
    union { float f_; uint i; } v; v.f_ = f;
    uint r = (v.i + 0x7FFFu + ((v.i >> 16) & 1u)) >> 16;
    return (bfu)r;
}

// ---------------------------------------------------------------- cooperative CSR build
// ONE kernel, 196 blocks x 512 threads, phases split by grid.sync():
// P0 zero counters; P1 bucket hist; P2 scan (redundant per-block, LDS);
// P3 bin edges into bucket-major `binned`; P4 per-bucket CSR + z0 epilogue.
__global__ __launch_bounds__(512) void csr_build_all(
    const int* __restrict__ src, const int* __restrict__ dst,
    int* __restrict__ gcount, int* __restrict__ gcursor,
    int* __restrict__ rowptr, float* __restrict__ dinv, int* __restrict__ nbr,
    const float4* __restrict__ x, ushort4* __restrict__ z0,
    uint* __restrict__ binned, int nN, int nE) {
    cg::grid_group grid = cg::this_grid();
    __shared__ int h[NBUCK];        // P1 local hist / P3 chunk hist
    __shared__ int sc[NBUCK];       // P2 scan
    __shared__ int lbase[NBUCK];    // P2: every block's private copy of bucket bases
    __shared__ int base2[NBUCK];    // P3: per-chunk global reservations
    __shared__ int hist2[512];      // P4
    __shared__ int cur2[512];       // P4
    int tid = threadIdx.x;
    int b = blockIdx.x;
    int nB = gridDim.x;

    // ---- P0: zero global counters
    for (int i = b * 512 + tid; i < NBUCK; i += nB * 512) gcount[i] = 0;
    grid.sync();

    // ---- P1: bucket histogram (LDS-local, one global atomic per bucket per block)
    if (tid < NBUCK) h[tid] = 0;
    __syncthreads();
    for (int e = b * 512 + tid; e < nE; e += nB * 512)
        atomicAdd(&h[dst[e] >> BSHIFT], 1);
    __syncthreads();
    if (tid < NBUCK && h[tid]) atomicAdd(&gcount[tid], h[tid]);
    grid.sync();

    // ---- P2: exclusive scan of gcount, redundantly in every block (no re-broadcast)
    {
        int v = (tid < NBUCK) ? gcount[tid] : 0;
        if (tid < NBUCK) sc[tid] = v;
        __syncthreads();
        #pragma unroll
        for (int off = 1; off < NBUCK; off <<= 1) {
            int t2 = (tid >= off && tid < NBUCK) ? sc[tid - off] : 0;
            __syncthreads();
            if (tid < NBUCK) sc[tid] += t2;
            __syncthreads();
        }
        if (tid < NBUCK) lbase[tid] = sc[tid] - v;
        if (b == 0 && tid < NBUCK) gcursor[tid] = sc[tid] - v;
    }
    grid.sync();

    // ---- P3: bin edges by bucket, grid-stride chunks of 4096
    for (int chunk = b; (size_t)chunk * 4096 < (size_t)nE; chunk += nB) {
        int start = chunk * 4096;
        if (tid < NBUCK) h[tid] = 0;
        __syncthreads();
        int bkt[8], rnk[8];
        #pragma unroll
        for (int u = 0; u < 8; ++u) {
            int e = start + u * 512 + tid;
            bkt[u] = -1;
            if (e < nE) {
                int bb = dst[e] >> BSHIFT;
                bkt[u] = bb;
                rnk[u] = atomicAdd(&h[bb], 1);
            }
        }
        __syncthreads();
        if (tid < NBUCK) base2[tid] = h[tid] ? atomicAdd(&gcursor[tid], h[tid]) : 0;
        __syncthreads();
        #pragma unroll
        for (int u = 0; u < 8; ++u) {
            int e = start + u * 512 + tid;
            if (e < nE) {
                uint pk = ((uint)(dst[e] & 511) << 17) | (uint)src[e];  // src < 2^17
                binned[base2[bkt[u]] + rnk[u]] = pk;
            }
        }
        __syncthreads();
    }
    grid.sync();

    // ---- P4: build bucket b (grid is exactly nBk blocks)
    {
        int n0 = b << BSHIFT;
        int nNodes = min(512, nN - n0);
        int base = lbase[b];
        int cnt = ((b + 1 < NBUCK) ? lbase[b + 1] : nE) - base;   // bucket size
        hist2[tid] = 0;
        __syncthreads();
        for (int i = tid; i < cnt; i += 512)
            atomicAdd(&hist2[binned[base + i] >> 17], 1);
        __syncthreads();
        int v = hist2[tid];
        #pragma unroll
        for (int off = 1; off < 512; off <<= 1) {
            int tv = (tid >= off) ? hist2[tid - off] : 0;
            __syncthreads();
            hist2[tid] += tv;
            __syncthreads();
        }
        int excl = hist2[tid] - v;
        float dv = rsqrtf((float)v + 1.0f);          // +1 self loop
        if (tid < nNodes) {
            rowptr[n0 + tid] = base + excl;
            dinv[n0 + tid] = dv;
        }
        cur2[tid] = excl;
        __syncthreads();
        ((float*)hist2)[tid] = dv;                    // reuse as dinv cache
        __syncthreads();
        for (int i = tid; i < cnt; i += 512) {
            uint pk = binned[base + i];
            int ld = pk >> 17;
            int pos = atomicAdd(&cur2[ld], 1);
            nbr[base + pos] = (int)(pk & 0x1FFFFu);
        }
        // z0 epilogue: bf16(dinv * x) for this bucket, coalesced
        const float4* xr = x + (size_t)n0 * 16;
        ushort4* zr = z0 + (size_t)n0 * 16;
        int totalF4 = nNodes * 16;
        for (int i = tid; i < totalF4; i += 512) {
            float w = ((float*)hist2)[i >> 4];
            float4 vv = xr[i];
            ushort4 o;
            o.x = f2bf(w * vv.x); o.y = f2bf(w * vv.y);
            o.z = f2bf(w * vv.z); o.w = f2bf(w * vv.w);
            zr[i] = o;
        }
        if (b == 0 && tid == 0) rowptr[nN] = nE;
    }
}

// ---------------------------------------------------------------- gather hop, 8 rows/load
template<int PW>
__global__ __launch_bounds__(256, 8) void gather_hop8(
    bfu* __restrict__ out, const bfu* __restrict__ z,
    const int* __restrict__ nbr, const int* __restrict__ rowptr,
    const float* __restrict__ dinv, int nN) {
    int node = blockIdx.x * 4 + (threadIdx.x >> 6);
    if (node >= nN) return;
    int lane = threadIdx.x & 63;
    int g = lane >> 3, k = lane & 7;
    int beg = rowptr[node], end = rowptr[node + 1];

    float acc[8];
    #pragma unroll
    for (int i = 0; i < 8; ++i) acc[i] = 0.f;

    auto rowload = [&](int s) -> uint4 {
        return reinterpret_cast<const uint4*>(z + (size_t)s * 64)[k];
    };
    auto accum = [&](uint4 v) {
        union { uint u; float f; } t;
        t.u = v.x << 16;         acc[0] += t.f;
        t.u = v.x & 0xFFFF0000u; acc[1] += t.f;
        t.u = v.y << 16;         acc[2] += t.f;
        t.u = v.y & 0xFFFF0000u; acc[3] += t.f;
        t.u = v.z << 16;         acc[4] += t.f;
        t.u = v.z & 0xFFFF0000u; acc[5] += t.f;
        t.u = v.w << 16;         acc[6] += t.f;
        t.u = v.w & 0xFFFF0000u; acc[7] += t.f;
    };

    if (g == 0)   // self loop
        accum(rowload(node));
    int j = beg + g;
    for (; j + 8 < end; j += 16) {
        int i0 = nbr[j], i1 = nbr[j + 8];
        uint4 v0 = rowload(i0);
        uint4 v1 = rowload(i1);
        accum(v0);
        accum(v1);
    }
    if (j < end)
        accum(rowload(nbr[j]));

    #pragma unroll
    for (int m = 8; m < 64; m <<= 1)
        #pragma unroll
        for (int i = 0; i < 8; ++i)
            acc[i] += __shfl_xor(acc[i], m);

    if (g == 0) {
        float di = dinv[node];
        float w = (PW == 2) ? di * di : di;
        uint4 o;
        o.x = ((uint)f2bf(acc[1] * w) << 16) | f2bf(acc[0] * w);
        o.y = ((uint)f2bf(acc[3] * w) << 16) | f2bf(acc[2] * w);
        o.z = ((uint)f2bf(acc[5] * w) << 16) | f2bf(acc[4] * w);
        o.w = ((uint)f2bf(acc[7] * w) << 16) | f2bf(acc[6] * w);
        reinterpret_cast<uint4*>(out + (size_t)node * 64)[k] = o;
    }
}

// ---------------------------------------------------------------- MFMA MLP + log_softmax
// block = 256 threads = 4 waves; wave = 16 nodes (M-tile).
__global__ __launch_bounds__(256) void mlp_mfma(
    float* __restrict__ out, const bfu* __restrict__ zC,
    const float* __restrict__ W1, const float* __restrict__ b1,
    const float* __restrict__ W2, const float* __restrict__ b2, int nN) {
    __shared__ short w1t[64 * 72];   // w1t[n][k] bf16
    __shared__ short w2t[48 * 72];   // w2t[n][k] bf16, n 40..47 = 0
    __shared__ short hlds[64 * 72];  // h[node][hid] bf16
    __shared__ float b1s[64];
    __shared__ float b2s[48];

    int tid = threadIdx.x;
    for (int i = tid; i < 64 * 64; i += 256) {
        int k = i >> 6, n = i & 63;
        w1t[n * 72 + k] = (short)f2bf(W1[i]);
    }
    for (int i = tid; i < 48 * 64; i += 256) {
        int k = i / 48, n = i % 48;
        w2t[n * 72 + k] = (short)(n < 40 ? f2bf(W2[k * 40 + n]) : 0);
    }
    if (tid < 64) b1s[tid] = b1[tid];
    if (tid >= 64 && tid < 112) b2s[tid - 64] = (tid - 64 < 40) ? b2[tid - 64] : 0.f;

    int wv = tid >> 6, l = tid & 63;
    int li = l & 15, kg = l >> 4;
    int nodebase = blockIdx.x * 64 + wv * 16;
    int nclamp = min(nodebase + li, nN - 1);

    const short8v* zr = (const short8v*)(zC + (size_t)nclamp * 64);
    short8v a0 = zr[kg];
    short8v a1 = zr[kg + 4];
    __syncthreads();

    f32x4 acc[4];
    #pragma unroll
    for (int nt = 0; nt < 4; ++nt) {
        f32x4 c = {0.f, 0.f, 0.f, 0.f};
        short8v b0 = *(const short8v*)&w1t[(nt * 16 + li) * 72 + kg * 8];
        short8v b1f = *(const short8v*)&w1t[(nt * 16 + li) * 72 + 32 + kg * 8];
        c = __builtin_amdgcn_mfma_f32_16x16x32_bf16(a0, b0, c, 0, 0, 0);
        c = __builtin_amdgcn_mfma_f32_16x16x32_bf16(a1, b1f, c, 0, 0, 0);
        acc[nt] = c;
    }
    #pragma unroll
    for (int nt = 0; nt < 4; ++nt) {
        float bb = b1s[nt * 16 + li];
        #pragma unroll
        for (int r = 0; r < 4; ++r) {
            float v = fmaxf(acc[nt][r] + bb, 0.f);
            hlds[(wv * 16 + kg * 4 + r) * 72 + nt * 16 + li] = (short)f2bf(v);
        }
    }
    __syncthreads();

    const short8v* hp = (const short8v*)&hlds[(wv * 16 + li) * 72];
    short8v ha0 = hp[kg];
    short8v ha1 = hp[kg + 4];
    f32x4 acc2[3];
    #pragma unroll
    for (int nt = 0; nt < 3; ++nt) {
        f32x4 c = {0.f, 0.f, 0.f, 0.f};
        short8v b0 = *(const short8v*)&w2t[(nt * 16 + li) * 72 + kg * 8];
        short8v b1f = *(const short8v*)&w2t[(nt * 16 + li) * 72 + 32 + kg * 8];
        c = __builtin_amdgcn_mfma_f32_16x16x32_bf16(ha0, b0, c, 0, 0, 0);
        c = __builtin_amdgcn_mfma_f32_16x16x32_bf16(ha1, b1f, c, 0, 0, 0);
        acc2[nt] = c;
    }

    float lg[3][4];
    #pragma unroll
    for (int nt = 0; nt < 3; ++nt) {
        float bb = b2s[nt * 16 + li];
        #pragma unroll
        for (int r = 0; r < 4; ++r) lg[nt][r] = acc2[nt][r] + bb;
    }
    bool v2 = (li < 8);
    float mx[4], sm[4];
    #pragma unroll
    for (int r = 0; r < 4; ++r) {
        float m = fmaxf(lg[0][r], lg[1][r]);
        if (v2) m = fmaxf(m, lg[2][r]);
        mx[r] = m;
    }
    #pragma unroll
    for (int off = 1; off < 16; off <<= 1)
        #pragma unroll
        for (int r = 0; r < 4; ++r)
            mx[r] = fmaxf(mx[r], __shfl_xor(mx[r], off));
    #pragma unroll
    for (int r = 0; r < 4; ++r) {
        float s = expf(lg[0][r] - mx[r]) + expf(lg[1][r] - mx[r]);
        if (v2) s += expf(lg[2][r] - mx[r]);
        sm[r] = s;
    }
    #pragma unroll
    for (int off = 1; off < 16; off <<= 1)
        #pragma unroll
        for (int r = 0; r < 4; ++r)
            sm[r] += __shfl_xor(sm[r], off);

    int nb2 = nodebase + kg * 4;
    #pragma unroll
    for (int r = 0; r < 4; ++r) {
        int nd = nb2 + r;
        if (nd < nN) {
            float lse = mx[r] + logf(sm[r]);
            out[(size_t)nd * 40 + li]      = lg[0][r] - lse;
            out[(size_t)nd * 40 + 16 + li] = lg[1][r] - lse;
            if (v2) out[(size_t)nd * 40 + 32 + li] = lg[2][r] - lse;
        }
    }
}

extern "C" void kernel_launch(void* const* d_in, const int* in_sizes, int n_in,
                              void* d_out, int out_size, void* d_ws, size_t ws_size,
                              hipStream_t stream) {
    const float* x   = (const float*)d_in[0];
    const int* eidx  = (const int*)d_in[1];
    const float* W1  = (const float*)d_in[2];
    const float* b1  = (const float*)d_in[3];
    const float* W2  = (const float*)d_in[4];
    const float* b2  = (const float*)d_in[5];
    float* out = (float*)d_out;

    const int nN = N_NODES;
    const int nE = in_sizes[1] / 2;  // edge_index is [2, E]
    const int* src = eidx;
    const int* dst = eidx + nE;
    const int nBk = (nN + 511) >> BSHIFT;   // 196 buckets

    // ---- workspace layout (256B aligned)
    char* ws = (char*)d_ws;
    size_t off = 0;
    auto alloc = [&](size_t bytes) {
        char* p = ws + off;
        off += (bytes + 255) & ~(size_t)255;
        return p;
    };
    float* dinv    = (float*)alloc((size_t)nN * 4);
    int*   gcount  = (int*)  alloc(NBUCK * 4);
    int*   gcursor = (int*)  alloc(NBUCK * 4);
    int*   rowptr  = (int*)  alloc((size_t)(nN + 1) * 4);
    uint*  binned  = (uint*) alloc((size_t)nE * 4);
    int*   nbr     = (int*)  alloc((size_t)nE * 4);
    bfu*   z0      = (bfu*)  alloc((size_t)nN * 64 * 2);
    bfu*   zB      = (bfu*)  alloc((size_t)nN * 64 * 2);
    bfu*   zC      = (bfu*)  alloc((size_t)nN * 64 * 2);

    // 1. fused cooperative CSR build (hist + scan + bin + per-bucket build + z0)
    {
        int nN_ = nN, nE_ = nE;
        const float4* x4 = (const float4*)x;
        ushort4* z04 = (ushort4*)z0;
        void* args[] = {(void*)&src, (void*)&dst, (void*)&gcount, (void*)&gcursor,
                        (void*)&rowptr, (void*)&dinv, (void*)&nbr,
                        (void*)&x4, (void*)&z04, (void*)&binned,
                        (void*)&nN_, (void*)&nE_};
        hipLaunchCooperativeKernel((void*)csr_build_all, dim3(nBk), dim3(512),
                                   args, 0, stream);
    }

    // 2. zB = bf16(D^-1 (A+I) z0); zC = bf16(D^-1/2 (A+I) zB)
    const int gBlocks = (nN + 3) / 4;
    gather_hop8<2><<<gBlocks, 256, 0, stream>>>(zB, z0, nbr, rowptr, dinv, nN);
    gather_hop8<1><<<gBlocks, 256, 0, stream>>>(zC, zB, nbr, rowptr, dinv, nN);

    // 3. MFMA MLP + log_softmax
    mlp_mfma<<<(nN + 63) / 64, 256, 0, stream>>>(out, zC, W1, b1, W2, b2, nN);
}

// Round 10
// 161.203 us; speedup vs baseline: 1.4826x; 1.4826x over previous
//
#include <hip/hip_runtime.h>
#include <math.h>

#define N_NODES 100000
#define BSHIFT 9                 // 512-node buckets
#define NBUCK 256                // >= ceil(N/512)=196, pow2 for arrays

typedef unsigned short bfu;
typedef unsigned int uint;
typedef __attribute__((ext_vector_type(8))) short short8v;   // 8 bf16 = 4 VGPRs
typedef __attribute__((ext_vector_type(4))) float f32x4;

__device__ __forceinline__ float bf2f(bfu u) {
    union { uint i; float f; } v; v.i = (uint)u << 16; return v.f;
}
__device__ __forceinline__ bfu f2bf(float f) {   // round-to-nearest-even
    union { float f_; uint i; } v; v.f_ = f;
    uint r = (v.i + 0x7FFFu + ((v.i >> 16) & 1u)) >> 16;
    return (bfu)r;
}

// ---------------------------------------------------------------- P0: bucket histogram
__global__ __launch_bounds__(256) void bucket_hist(const int* __restrict__ dst,
                                                   int* __restrict__ gcount, int nE) {
    __shared__ int h[NBUCK];
    int tid = threadIdx.x;
    h[tid] = 0;
    __syncthreads();
    for (int e = blockIdx.x * 256 + tid; e < nE; e += gridDim.x * 256)
        atomicAdd(&h[dst[e] >> BSHIFT], 1);
    __syncthreads();
    if (h[tid]) atomicAdd(&gcount[tid], h[tid]);
}

// ---------------------------------------------------------------- P0b: scan bucket counts
__global__ __launch_bounds__(NBUCK) void scan_buckets(const int* __restrict__ gcount,
                                                      int* __restrict__ gbase,
                                                      int* __restrict__ gcursor) {
    __shared__ int s[NBUCK];
    int t = threadIdx.x;
    int v = gcount[t];
    s[t] = v;
    __syncthreads();
    #pragma unroll
    for (int off = 1; off < NBUCK; off <<= 1) {
        int tv = (t >= off) ? s[t - off] : 0;
        __syncthreads();
        s[t] += tv;
        __syncthreads();
    }
    gbase[t] = s[t] - v;     // exclusive
    gcursor[t] = s[t] - v;
}

// ---------------------------------------------------------------- P1: bin edges by bucket
__global__ __launch_bounds__(256) void bin_edges(const int* __restrict__ src,
                                                 const int* __restrict__ dst,
                                                 int* __restrict__ gcursor,
                                                 uint* __restrict__ binned, int nE) {
    __shared__ int h[NBUCK];
    __shared__ int base[NBUCK];
    int tid = threadIdx.x;
    int start = blockIdx.x * 4096;
    h[tid] = 0;
    __syncthreads();
    int bkt[16], rnk[16];
    #pragma unroll
    for (int u = 0; u < 16; ++u) {
        int e = start + u * 256 + tid;
        bkt[u] = -1;
        if (e < nE) {
            int b = dst[e] >> BSHIFT;
            bkt[u] = b;
            rnk[u] = atomicAdd(&h[b], 1);
        }
    }
    __syncthreads();
    base[tid] = h[tid] ? atomicAdd(&gcursor[tid], h[tid]) : 0;
    __syncthreads();
    #pragma unroll
    for (int u = 0; u < 16; ++u) {
        int e = start + u * 256 + tid;
        if (e < nE) {
            uint pk = ((uint)(dst[e] & 511) << 17) | (uint)src[e];  // src < 2^17
            binned[base[bkt[u]] + rnk[u]] = pk;
        }
    }
}

// ---------------------------------------------------------------- P2: per-bucket CSR build
// rowptr + dinv + nbr scatter, then epilogue: z0 = bf16(dinv * x) for this
// bucket's nodes (coalesced float4->ushort4, dinv from LDS).
__global__ __launch_bounds__(512) void build_csr(
    const uint* __restrict__ binned, const int* __restrict__ gbase,
    const int* __restrict__ gcount, int* __restrict__ rowptr,
    float* __restrict__ dinv, int* __restrict__ nbr,
    const float4* __restrict__ x, ushort4* __restrict__ z0, int nN, int nE) {
    __shared__ int hist[512];
    __shared__ int cursor[512];
    int b = blockIdx.x, t = threadIdx.x;
    int n0 = b << BSHIFT;
    int nNodes = min(512, nN - n0);
    int base = gbase[b], cnt = gcount[b];
    hist[t] = 0;
    __syncthreads();
    for (int i = t; i < cnt; i += 512)
        atomicAdd(&hist[binned[base + i] >> 17], 1);
    __syncthreads();
    int v = hist[t];
    #pragma unroll
    for (int off = 1; off < 512; off <<= 1) {
        int tv = (t >= off) ? hist[t - off] : 0;
        __syncthreads();
        hist[t] += tv;
        __syncthreads();
    }
    int excl = hist[t] - v;
    float dv = rsqrtf((float)v + 1.0f);           // +1 self loop
    if (t < nNodes) {
        rowptr[n0 + t] = base + excl;
        dinv[n0 + t] = dv;
    }
    cursor[t] = excl;
    ((float*)hist)[t] = dv;                        // hist reused as dinv cache
    __syncthreads();
    for (int i = t; i < cnt; i += 512) {
        uint pk = binned[base + i];
        int ld = pk >> 17;
        int pos = atomicAdd(&cursor[ld], 1);
        nbr[base + pos] = (int)(pk & 0x1FFFFu);
    }
    // epilogue: z0 rows for this bucket (independent of scatter above)
    const float4* xr = x + (size_t)n0 * 16;
    ushort4* zr = z0 + (size_t)n0 * 16;
    int totalF4 = nNodes * 16;
    for (int i = t; i < totalF4; i += 512) {
        float w = ((float*)hist)[i >> 4];
        float4 vv = xr[i];
        ushort4 o;
        o.x = f2bf(w * vv.x); o.y = f2bf(w * vv.y);
        o.z = f2bf(w * vv.z); o.w = f2bf(w * vv.w);
        zr[i] = o;
    }
    if (b == 0 && t == 0) rowptr[nN] = nE;
}

// ---------------------------------------------------------------- gather hop, 8 rows/load
template<int PW>
__global__ __launch_bounds__(256, 8) void gather_hop8(
    bfu* __restrict__ out, const bfu* __restrict__ z,
    const int* __restrict__ nbr, const int* __restrict__ rowptr,
    const float* __restrict__ dinv, int nN) {
    int node = blockIdx.x * 4 + (threadIdx.x >> 6);
    if (node >= nN) return;
    int lane = threadIdx.x & 63;
    int g = lane >> 3, k = lane & 7;
    int beg = rowptr[node], end = rowptr[node + 1];

    float acc[8];
    #pragma unroll
    for (int i = 0; i < 8; ++i) acc[i] = 0.f;

    auto rowload = [&](int s) -> uint4 {
        return reinterpret_cast<const uint4*>(z + (size_t)s * 64)[k];
    };
    auto accum = [&](uint4 v) {
        union { uint u; float f; } t;
        t.u = v.x << 16;         acc[0] += t.f;
        t.u = v.x & 0xFFFF0000u; acc[1] += t.f;
        t.u = v.y << 16;         acc[2] += t.f;
        t.u = v.y & 0xFFFF0000u; acc[3] += t.f;
        t.u = v.z << 16;         acc[4] += t.f;
        t.u = v.z & 0xFFFF0000u; acc[5] += t.f;
        t.u = v.w << 16;         acc[6] += t.f;
        t.u = v.w & 0xFFFF0000u; acc[7] += t.f;
    };

    if (g == 0)   // self loop
        accum(rowload(node));
    int j = beg + g;
    for (; j + 8 < end; j += 16) {
        int i0 = nbr[j], i1 = nbr[j + 8];
        uint4 v0 = rowload(i0);
        uint4 v1 = rowload(i1);
        accum(v0);
        accum(v1);
    }
    if (j < end)
        accum(rowload(nbr[j]));

    #pragma unroll
    for (int m = 8; m < 64; m <<= 1)
        #pragma unroll
        for (int i = 0; i < 8; ++i)
            acc[i] += __shfl_xor(acc[i], m);

    if (g == 0) {
        float di = dinv[node];
        float w = (PW == 2) ? di * di : di;
        uint4 o;
        o.x = ((uint)f2bf(acc[1] * w) << 16) | f2bf(acc[0] * w);
        o.y = ((uint)f2bf(acc[3] * w) << 16) | f2bf(acc[2] * w);
        o.z = ((uint)f2bf(acc[5] * w) << 16) | f2bf(acc[4] * w);
        o.w = ((uint)f2bf(acc[7] * w) << 16) | f2bf(acc[6] * w);
        reinterpret_cast<uint4*>(out + (size_t)node * 64)[k] = o;
    }
}

// ---------------------------------------------------------------- MFMA MLP + log_softmax
// PERSISTENT: each block stages weights ONCE, then grid-strides over 64-node
// tiles. Loop-top barrier recycles hlds (orders prior LDS reads before writes).
__global__ __launch_bounds__(256) void mlp_mfma(
    float* __restrict__ out, const bfu* __restrict__ zC,
    const float* __restrict__ W1, const float* __restrict__ b1,
    const float* __restrict__ W2, const float* __restrict__ b2,
    int nN, int nTiles) {
    __shared__ short w1t[64 * 72];   // w1t[n][k] bf16
    __shared__ short w2t[48 * 72];   // w2t[n][k] bf16, n 40..47 = 0
    __shared__ short hlds[64 * 72];  // h[node][hid] bf16
    __shared__ float b1s[64];
    __shared__ float b2s[48];

    int tid = threadIdx.x;
    for (int i = tid; i < 64 * 64; i += 256) {       // read W1 coalesced
        int k = i >> 6, n = i & 63;
        w1t[n * 72 + k] = (short)f2bf(W1[i]);
    }
    for (int i = tid; i < 48 * 64; i += 256) {       // read W2 row-chunks
        int k = i / 48, n = i % 48;
        w2t[n * 72 + k] = (short)(n < 40 ? f2bf(W2[k * 40 + n]) : 0);
    }
    if (tid < 64) b1s[tid] = b1[tid];
    if (tid >= 64 && tid < 112) b2s[tid - 64] = (tid - 64 < 40) ? b2[tid - 64] : 0.f;

    int wv = tid >> 6, l = tid & 63;
    int li = l & 15, kg = l >> 4;                    // lane-in-16, k-group 0..3

    for (int tile = blockIdx.x; tile < nTiles; tile += gridDim.x) {
        int nodebase = tile * 64 + wv * 16;
        int nclamp = min(nodebase + li, nN - 1);

        // A fragments straight from global zC (row = li, k = kg*8+j / +32)
        const short8v* zr = (const short8v*)(zC + (size_t)nclamp * 64);
        short8v a0 = zr[kg];
        short8v a1 = zr[kg + 4];
        __syncthreads();   // weights staged (iter 0); hlds readers done (iter >0)

        // stage 1: 4 N-tiles x 2 K-steps
        f32x4 acc[4];
        #pragma unroll
        for (int nt = 0; nt < 4; ++nt) {
            f32x4 c = {0.f, 0.f, 0.f, 0.f};
            short8v b0 = *(const short8v*)&w1t[(nt * 16 + li) * 72 + kg * 8];
            short8v b1f = *(const short8v*)&w1t[(nt * 16 + li) * 72 + 32 + kg * 8];
            c = __builtin_amdgcn_mfma_f32_16x16x32_bf16(a0, b0, c, 0, 0, 0);
            c = __builtin_amdgcn_mfma_f32_16x16x32_bf16(a1, b1f, c, 0, 0, 0);
            acc[nt] = c;
        }
        #pragma unroll
        for (int nt = 0; nt < 4; ++nt) {
            float bb = b1s[nt * 16 + li];
            #pragma unroll
            for (int r = 0; r < 4; ++r) {
                float v = fmaxf(acc[nt][r] + bb, 0.f);
                hlds[(wv * 16 + kg * 4 + r) * 72 + nt * 16 + li] = (short)f2bf(v);
            }
        }
        __syncthreads();

        // stage 2: A from hlds, 3 N-tiles x 2 K-steps
        const short8v* hp = (const short8v*)&hlds[(wv * 16 + li) * 72];
        short8v ha0 = hp[kg];
        short8v ha1 = hp[kg + 4];
        f32x4 acc2[3];
        #pragma unroll
        for (int nt = 0; nt < 3; ++nt) {
            f32x4 c = {0.f, 0.f, 0.f, 0.f};
            short8v b0 = *(const short8v*)&w2t[(nt * 16 + li) * 72 + kg * 8];
            short8v b1f = *(const short8v*)&w2t[(nt * 16 + li) * 72 + 32 + kg * 8];
            c = __builtin_amdgcn_mfma_f32_16x16x32_bf16(ha0, b0, c, 0, 0, 0);
            c = __builtin_amdgcn_mfma_f32_16x16x32_bf16(ha1, b1f, c, 0, 0, 0);
            acc2[nt] = c;
        }

        // log_softmax: node = nodebase + kg*4 + r; cols nt*16+li (valid < 40)
        float lg[3][4];
        #pragma unroll
        for (int nt = 0; nt < 3; ++nt) {
            float bb = b2s[nt * 16 + li];
            #pragma unroll
            for (int r = 0; r < 4; ++r) lg[nt][r] = acc2[nt][r] + bb;
        }
        bool v2 = (li < 8);   // tile 2 valid cols 32..39
        float mx[4], sm[4];
        #pragma unroll
        for (int r = 0; r < 4; ++r) {
            float m = fmaxf(lg[0][r], lg[1][r]);
            if (v2) m = fmaxf(m, lg[2][r]);
            mx[r] = m;
        }
        #pragma unroll
        for (int off = 1; off < 16; off <<= 1)
            #pragma unroll
            for (int r = 0; r < 4; ++r)
                mx[r] = fmaxf(mx[r], __shfl_xor(mx[r], off));
        #pragma unroll
        for (int r = 0; r < 4; ++r) {
            float s = expf(lg[0][r] - mx[r]) + expf(lg[1][r] - mx[r]);
            if (v2) s += expf(lg[2][r] - mx[r]);
            sm[r] = s;
        }
        #pragma unroll
        for (int off = 1; off < 16; off <<= 1)
            #pragma unroll
            for (int r = 0; r < 4; ++r)
                sm[r] += __shfl_xor(sm[r], off);

        int nb2 = nodebase + kg * 4;
        #pragma unroll
        for (int r = 0; r < 4; ++r) {
            int nd = nb2 + r;
            if (nd < nN) {
                float lse = mx[r] + logf(sm[r]);
                out[(size_t)nd * 40 + li]      = lg[0][r] - lse;
                out[(size_t)nd * 40 + 16 + li] = lg[1][r] - lse;
                if (v2) out[(size_t)nd * 40 + 32 + li] = lg[2][r] - lse;
            }
        }
    }
}

extern "C" void kernel_launch(void* const* d_in, const int* in_sizes, int n_in,
                              void* d_out, int out_size, void* d_ws, size_t ws_size,
                              hipStream_t stream) {
    const float* x   = (const float*)d_in[0];
    const int* eidx  = (const int*)d_in[1];
    const float* W1  = (const float*)d_in[2];
    const float* b1  = (const float*)d_in[3];
    const float* W2  = (const float*)d_in[4];
    const float* b2  = (const float*)d_in[5];
    float* out = (float*)d_out;

    const int nN = N_NODES;
    const int nE = in_sizes[1] / 2;  // edge_index is [2, E]
    const int* src = eidx;
    const int* dst = eidx + nE;
    const int nBk = (nN + 511) >> BSHIFT;   // 196 buckets

    // ---- workspace layout (256B aligned)
    char* ws = (char*)d_ws;
    size_t off = 0;
    auto alloc = [&](size_t bytes) {
        char* p = ws + off;
        off += (bytes + 255) & ~(size_t)255;
        return p;
    };
    float* dinv    = (float*)alloc((size_t)nN * 4);
    int*   gcount  = (int*)  alloc(NBUCK * 4);
    int*   gbase   = (int*)  alloc(NBUCK * 4);
    int*   gcursor = (int*)  alloc(NBUCK * 4);
    int*   rowptr  = (int*)  alloc((size_t)(nN + 1) * 4);
    uint*  binned  = (uint*) alloc((size_t)nE * 4);
    int*   nbr     = (int*)  alloc((size_t)nE * 4);
    bfu*   z0      = (bfu*)  alloc((size_t)nN * 64 * 2);
    bfu*   zB      = (bfu*)  alloc((size_t)nN * 64 * 2);
    bfu*   zC      = (bfu*)  alloc((size_t)nN * 64 * 2);

    // 1. CSR build: hist -> scan -> bin -> per-bucket build (rowptr, dinv, nbr, z0)
    hipMemsetAsync(gcount, 0, NBUCK * 4, stream);
    bucket_hist<<<640, 256, 0, stream>>>(dst, gcount, nE);
    scan_buckets<<<1, NBUCK, 0, stream>>>(gcount, gbase, gcursor);
    bin_edges<<<(nE + 4095) / 4096, 256, 0, stream>>>(src, dst, gcursor, binned, nE);
    build_csr<<<nBk, 512, 0, stream>>>(binned, gbase, gcount, rowptr, dinv, nbr,
                                       (const float4*)x, (ushort4*)z0, nN, nE);

    // 2. zB = bf16(D^-1 (A+I) z0); zC = bf16(D^-1/2 (A+I) zB)
    const int gBlocks = (nN + 3) / 4;
    gather_hop8<2><<<gBlocks, 256, 0, stream>>>(zB, z0, nbr, rowptr, dinv, nN);
    gather_hop8<1><<<gBlocks, 256, 0, stream>>>(zC, zB, nbr, rowptr, dinv, nN);

    // 3. persistent MFMA MLP + log_softmax
    const int nTiles = (nN + 63) / 64;
    mlp_mfma<<<392, 256, 0, stream>>>(out, zC, W1, b1, W2, b2, nN, nTiles);
}

// Round 11
// 144.542 us; speedup vs baseline: 1.6535x; 1.1153x over previous
//
#include <hip/hip_runtime.h>
#include <math.h>

#define N_NODES 100000
#define BSHIFT 9                 // 512-node buckets
#define NBUCK 256                // >= ceil(N/512)=196, pow2
#define CAPSHIFT 13              // 8192 slots per bucket (mean 6122, +26 sigma)
#define CAP (1 << CAPSHIFT)

typedef unsigned short bfu;
typedef unsigned int uint;
typedef __attribute__((ext_vector_type(8))) short short8v;   // 8 bf16 = 4 VGPRs
typedef __attribute__((ext_vector_type(4))) float f32x4;
typedef __attribute__((ext_vector_type(2))) float f32x2;

__device__ __forceinline__ float bf2f(bfu u) {
    union { uint i; float f; } v; v.i = (uint)u << 16; return v.f;
}
__device__ __forceinline__ bfu f2bf(float f) {   // round-to-nearest-even
    union { float f_; uint i; } v; v.f_ = f;
    uint r = (v.i + 0x7FFFu + ((v.i >> 16) & 1u)) >> 16;
    return (bfu)r;
}
__device__ __forceinline__ float asf(uint u) {
    union { uint i; float f; } v; v.i = u; return v.f;
}

// ---------------------------------------------------------------- P1: bin edges by bucket
// Static bucket bases (b*CAP); per-chunk reservation via gcursor atomics.
__global__ __launch_bounds__(256) void bin_edges(const int* __restrict__ src,
                                                 const int* __restrict__ dst,
                                                 int* __restrict__ gcursor,
                                                 uint* __restrict__ binned, int nE) {
    __shared__ int h[NBUCK];
    __shared__ int base[NBUCK];
    int tid = threadIdx.x;
    int start = blockIdx.x * 4096;
    h[tid] = 0;
    __syncthreads();
    int bkt[16], rnk[16];
    #pragma unroll
    for (int u = 0; u < 16; ++u) {
        int e = start + u * 256 + tid;
        bkt[u] = -1;
        if (e < nE) {
            int b = dst[e] >> BSHIFT;
            bkt[u] = b;
            rnk[u] = atomicAdd(&h[b], 1);
        }
    }
    __syncthreads();
    base[tid] = h[tid] ? (tid << CAPSHIFT) + atomicAdd(&gcursor[tid], h[tid]) : 0;
    __syncthreads();
    #pragma unroll
    for (int u = 0; u < 16; ++u) {
        int e = start + u * 256 + tid;
        if (e < nE) {
            uint pk = ((uint)(dst[e] & 511) << 17) | (uint)src[e];  // src < 2^17
            binned[base[bkt[u]] + rnk[u]] = pk;
        }
    }
}

// ---------------------------------------------------------------- P2: per-bucket CSR build
// Gapped bucket-major nbr; rowptr/rowend per node; z0 = bf16(dinv*x) epilogue.
__global__ __launch_bounds__(512) void build_csr(
    const uint* __restrict__ binned, const int* __restrict__ gcursor,
    int* __restrict__ rowptr, int* __restrict__ rowend,
    float* __restrict__ dinv, int* __restrict__ nbr,
    const float4* __restrict__ x, ushort4* __restrict__ z0, int nN) {
    __shared__ int hist[512];
    __shared__ int cursor[512];
    int b = blockIdx.x, t = threadIdx.x;
    int n0 = b << BSHIFT;
    int nNodes = min(512, nN - n0);
    int base = b << CAPSHIFT;
    int cnt = gcursor[b];
    hist[t] = 0;
    __syncthreads();
    for (int i = t; i < cnt; i += 512)
        atomicAdd(&hist[binned[base + i] >> 17], 1);
    __syncthreads();
    int v = hist[t];
    #pragma unroll
    for (int off = 1; off < 512; off <<= 1) {
        int tv = (t >= off) ? hist[t - off] : 0;
        __syncthreads();
        hist[t] += tv;
        __syncthreads();
    }
    int excl = hist[t] - v;
    float dv = rsqrtf((float)v + 1.0f);           // +1 self loop
    if (t < nNodes) {
        rowptr[n0 + t] = base + excl;
        rowend[n0 + t] = base + excl + v;
        dinv[n0 + t] = dv;
    }
    cursor[t] = excl;
    __syncthreads();
    ((float*)hist)[t] = dv;                        // hist reused as dinv cache
    __syncthreads();
    for (int i = t; i < cnt; i += 512) {
        uint pk = binned[base + i];
        int ld = pk >> 17;
        int pos = atomicAdd(&cursor[ld], 1);
        nbr[base + pos] = (int)(pk & 0x1FFFFu);
    }
    // epilogue: z0 rows for this bucket, coalesced
    const float4* xr = x + (size_t)n0 * 16;
    ushort4* zr = z0 + (size_t)n0 * 16;
    int totalF4 = nNodes * 16;
    for (int i = t; i < totalF4; i += 512) {
        float w = ((float*)hist)[i >> 4];
        float4 vv = xr[i];
        ushort4 o;
        o.x = f2bf(w * vv.x); o.y = f2bf(w * vv.y);
        o.z = f2bf(w * vv.z); o.w = f2bf(w * vv.w);
        zr[i] = o;
    }
}

// ---------------------------------------------------------------- gather hop, 8 rows/load
// wave = 1 node; 8 groups of 8 lanes; unroll-2 over the 8-stride; f32x2
// accumulators to encourage v_pk_add_f32 packed adds.
template<int PW>
__global__ __launch_bounds__(256, 8) void gather_hop8(
    bfu* __restrict__ out, const bfu* __restrict__ z,
    const int* __restrict__ nbr, const int* __restrict__ rowptr,
    const int* __restrict__ rowend, const float* __restrict__ dinv, int nN) {
    int node = blockIdx.x * 4 + (threadIdx.x >> 6);
    if (node >= nN) return;
    int lane = threadIdx.x & 63;
    int g = lane >> 3, k = lane & 7;
    int beg = rowptr[node], end = rowend[node];

    f32x2 a0 = {0.f, 0.f}, a1 = {0.f, 0.f}, a2 = {0.f, 0.f}, a3 = {0.f, 0.f};

    auto rowload = [&](int s) -> uint4 {
        return reinterpret_cast<const uint4*>(z + (size_t)s * 64)[k];
    };
    auto accum = [&](uint4 v) {
        f32x2 p;
        p.x = asf(v.x << 16); p.y = asf(v.x & 0xFFFF0000u); a0 += p;
        p.x = asf(v.y << 16); p.y = asf(v.y & 0xFFFF0000u); a1 += p;
        p.x = asf(v.z << 16); p.y = asf(v.z & 0xFFFF0000u); a2 += p;
        p.x = asf(v.w << 16); p.y = asf(v.w & 0xFFFF0000u); a3 += p;
    };

    if (g == 0)   // self loop
        accum(rowload(node));
    int j = beg + g;
    for (; j + 8 < end; j += 16) {
        int i0 = nbr[j], i1 = nbr[j + 8];
        uint4 v0 = rowload(i0);
        uint4 v1 = rowload(i1);
        accum(v0);
        accum(v1);
    }
    if (j < end)
        accum(rowload(nbr[j]));

    float acc[8] = {a0.x, a0.y, a1.x, a1.y, a2.x, a2.y, a3.x, a3.y};
    #pragma unroll
    for (int m = 8; m < 64; m <<= 1)
        #pragma unroll
        for (int i = 0; i < 8; ++i)
            acc[i] += __shfl_xor(acc[i], m);

    if (g == 0) {
        float di = dinv[node];
        float w = (PW == 2) ? di * di : di;
        uint4 o;
        o.x = ((uint)f2bf(acc[1] * w) << 16) | f2bf(acc[0] * w);
        o.y = ((uint)f2bf(acc[3] * w) << 16) | f2bf(acc[2] * w);
        o.z = ((uint)f2bf(acc[5] * w) << 16) | f2bf(acc[4] * w);
        o.w = ((uint)f2bf(acc[7] * w) << 16) | f2bf(acc[6] * w);
        reinterpret_cast<uint4*>(out + (size_t)node * 64)[k] = o;
    }
}

// ---------------------------------------------------------------- MFMA MLP + log_softmax
// PERSISTENT: each block stages weights ONCE, then grid-strides over 64-node tiles.
__global__ __launch_bounds__(256) void mlp_mfma(
    float* __restrict__ out, const bfu* __restrict__ zC,
    const float* __restrict__ W1, const float* __restrict__ b1,
    const float* __restrict__ W2, const float* __restrict__ b2,
    int nN, int nTiles) {
    __shared__ short w1t[64 * 72];   // w1t[n][k] bf16
    __shared__ short w2t[48 * 72];   // w2t[n][k] bf16, n 40..47 = 0
    __shared__ short hlds[64 * 72];  // h[node][hid] bf16
    __shared__ float b1s[64];
    __shared__ float b2s[48];

    int tid = threadIdx.x;
    for (int i = tid; i < 64 * 64; i += 256) {
        int k = i >> 6, n = i & 63;
        w1t[n * 72 + k] = (short)f2bf(W1[i]);
    }
    for (int i = tid; i < 48 * 64; i += 256) {
        int k = i / 48, n = i % 48;
        w2t[n * 72 + k] = (short)(n < 40 ? f2bf(W2[k * 40 + n]) : 0);
    }
    if (tid < 64) b1s[tid] = b1[tid];
    if (tid >= 64 && tid < 112) b2s[tid - 64] = (tid - 64 < 40) ? b2[tid - 64] : 0.f;

    int wv = tid >> 6, l = tid & 63;
    int li = l & 15, kg = l >> 4;

    for (int tile = blockIdx.x; tile < nTiles; tile += gridDim.x) {
        int nodebase = tile * 64 + wv * 16;
        int nclamp = min(nodebase + li, nN - 1);

        const short8v* zr = (const short8v*)(zC + (size_t)nclamp * 64);
        short8v a0 = zr[kg];
        short8v a1 = zr[kg + 4];
        __syncthreads();   // weights staged (iter 0); hlds readers done (iter >0)

        f32x4 acc[4];
        #pragma unroll
        for (int nt = 0; nt < 4; ++nt) {
            f32x4 c = {0.f, 0.f, 0.f, 0.f};
            short8v b0 = *(const short8v*)&w1t[(nt * 16 + li) * 72 + kg * 8];
            short8v b1f = *(const short8v*)&w1t[(nt * 16 + li) * 72 + 32 + kg * 8];
            c = __builtin_amdgcn_mfma_f32_16x16x32_bf16(a0, b0, c, 0, 0, 0);
            c = __builtin_amdgcn_mfma_f32_16x16x32_bf16(a1, b1f, c, 0, 0, 0);
            acc[nt] = c;
        }
        #pragma unroll
        for (int nt = 0; nt < 4; ++nt) {
            float bb = b1s[nt * 16 + li];
            #pragma unroll
            for (int r = 0; r < 4; ++r) {
                float v = fmaxf(acc[nt][r] + bb, 0.f);
                hlds[(wv * 16 + kg * 4 + r) * 72 + nt * 16 + li] = (short)f2bf(v);
            }
        }
        __syncthreads();

        const short8v* hp = (const short8v*)&hlds[(wv * 16 + li) * 72];
        short8v ha0 = hp[kg];
        short8v ha1 = hp[kg + 4];
        f32x4 acc2[3];
        #pragma unroll
        for (int nt = 0; nt < 3; ++nt) {
            f32x4 c = {0.f, 0.f, 0.f, 0.f};
            short8v b0 = *(const short8v*)&w2t[(nt * 16 + li) * 72 + kg * 8];
            short8v b1f = *(const short8v*)&w2t[(nt * 16 + li) * 72 + 32 + kg * 8];
            c = __builtin_amdgcn_mfma_f32_16x16x32_bf16(ha0, b0, c, 0, 0, 0);
            c = __builtin_amdgcn_mfma_f32_16x16x32_bf16(ha1, b1f, c, 0, 0, 0);
            acc2[nt] = c;
        }

        float lg[3][4];
        #pragma unroll
        for (int nt = 0; nt < 3; ++nt) {
            float bb = b2s[nt * 16 + li];
            #pragma unroll
            for (int r = 0; r < 4; ++r) lg[nt][r] = acc2[nt][r] + bb;
        }
        bool v2 = (li < 8);   // tile 2 valid cols 32..39
        float mx[4], sm[4];
        #pragma unroll
        for (int r = 0; r < 4; ++r) {
            float m = fmaxf(lg[0][r], lg[1][r]);
            if (v2) m = fmaxf(m, lg[2][r]);
            mx[r] = m;
        }
        #pragma unroll
        for (int off = 1; off < 16; off <<= 1)
            #pragma unroll
            for (int r = 0; r < 4; ++r)
                mx[r] = fmaxf(mx[r], __shfl_xor(mx[r], off));
        #pragma unroll
        for (int r = 0; r < 4; ++r) {
            float s = expf(lg[0][r] - mx[r]) + expf(lg[1][r] - mx[r]);
            if (v2) s += expf(lg[2][r] - mx[r]);
            sm[r] = s;
        }
        #pragma unroll
        for (int off = 1; off < 16; off <<= 1)
            #pragma unroll
            for (int r = 0; r < 4; ++r)
                sm[r] += __shfl_xor(sm[r], off);

        int nb2 = nodebase + kg * 4;
        #pragma unroll
        for (int r = 0; r < 4; ++r) {
            int nd = nb2 + r;
            if (nd < nN) {
                float lse = mx[r] + logf(sm[r]);
                out[(size_t)nd * 40 + li]      = lg[0][r] - lse;
                out[(size_t)nd * 40 + 16 + li] = lg[1][r] - lse;
                if (v2) out[(size_t)nd * 40 + 32 + li] = lg[2][r] - lse;
            }
        }
    }
}

extern "C" void kernel_launch(void* const* d_in, const int* in_sizes, int n_in,
                              void* d_out, int out_size, void* d_ws, size_t ws_size,
                              hipStream_t stream) {
    const float* x   = (const float*)d_in[0];
    const int* eidx  = (const int*)d_in[1];
    const float* W1  = (const float*)d_in[2];
    const float* b1  = (const float*)d_in[3];
    const float* W2  = (const float*)d_in[4];
    const float* b2  = (const float*)d_in[5];
    float* out = (float*)d_out;

    const int nN = N_NODES;
    const int nE = in_sizes[1] / 2;  // edge_index is [2, E]
    const int* src = eidx;
    const int* dst = eidx + nE;
    const int nBk = (nN + 511) >> BSHIFT;   // 196 buckets

    // ---- workspace layout (256B aligned)
    char* ws = (char*)d_ws;
    size_t off = 0;
    auto alloc = [&](size_t bytes) {
        char* p = ws + off;
        off += (bytes + 255) & ~(size_t)255;
        return p;
    };
    float* dinv    = (float*)alloc((size_t)nN * 4);
    int*   gcursor = (int*)  alloc(NBUCK * 4);
    int*   rowptr  = (int*)  alloc((size_t)nN * 4);
    int*   rowend  = (int*)  alloc((size_t)nN * 4);
    uint*  binned  = (uint*) alloc((size_t)NBUCK * CAP * 4);   // 8 MB, gapped
    int*   nbr     = (int*)  alloc((size_t)NBUCK * CAP * 4);   // 8 MB, gapped
    bfu*   z0      = (bfu*)  alloc((size_t)nN * 64 * 2);
    bfu*   zB      = (bfu*)  alloc((size_t)nN * 64 * 2);
    bfu*   zC      = (bfu*)  alloc((size_t)nN * 64 * 2);

    // 1. CSR build: bin (static bucket bases) -> per-bucket build (+dinv, z0)
    hipMemsetAsync(gcursor, 0, NBUCK * 4, stream);
    bin_edges<<<(nE + 4095) / 4096, 256, 0, stream>>>(src, dst, gcursor, binned, nE);
    build_csr<<<nBk, 512, 0, stream>>>(binned, gcursor, rowptr, rowend, dinv, nbr,
                                       (const float4*)x, (ushort4*)z0, nN);

    // 2. zB = bf16(D^-1 (A+I) z0); zC = bf16(D^-1/2 (A+I) zB)
    const int gBlocks = (nN + 3) / 4;
    gather_hop8<2><<<gBlocks, 256, 0, stream>>>(zB, z0, nbr, rowptr, rowend, dinv, nN);
    gather_hop8<1><<<gBlocks, 256, 0, stream>>>(zC, zB, nbr, rowptr, rowend, dinv, nN);

    // 3. persistent MFMA MLP + log_softmax
    const int nTiles = (nN + 63) / 64;
    mlp_mfma<<<392, 256, 0, stream>>>(out, zC, W1, b1, W2, b2, nN, nTiles);
}